// Round 6
// baseline (201.599 us; speedup 1.0000x reference)
//
#include <hip/hip_runtime.h>

// SSIM fused, v15: 1-wave workgroups -> guaranteed 12 waves/CU.
// v14 post-mortem: occupancy stayed 25% (predicted 35) -- 3x53248B = 159744
// vs 160KiB LDS is a marginal fit and the runtime reserve dropped us to
// 2 blocks/CU = v13's residency with shallower prefetch -> 48us (no progress).
// Invariant across v9..v14: 46-53us at occ 16/25/65%, FETCH at the 99MB
// floor, VALU busy ~8us, BW floor ~16us. Residual ~30us = per-granule serial
// chain + load latency with only 2 waves/SIMD to cover it. The untested cell
// is >=3 waves/SIMD WITH the async pipeline. v15:
//   - block = 1 wave (64 thr), LDS/block 13312B (raw 2-slot 8KB + H 5KB):
//     floor(163840/13312) = 12 blocks/CU = 3 waves/SIMD, robust to reserve.
//   - grid 32x2x48 = 3072 blocks = exactly 12/CU, one residency round.
//   - no __syncthreads / block reduce: per-wave partial stored directly.
//   - k-loop fully unrolled (compile-time k: no per-iter address VALU,
//     compile-time edge flags).
//   - pipeline/math/edges byte-identical to harness-verified v14: 2-slot raw
//     ring, issue k+2 after consuming k (distance-2), vmcnt(4) steady /
//     4 / 0 tail; lgkmcnt(0)+sched_barrier before slot reuse (WAR);
//     H ring 2 slots (g&1), window (quad*8+o*16)&31; band via __shfl.
// Single-variable test: does TLP 8->12 waves/CU scale the stall? If dur
// stays ~46-48, the granule chain itself binds -> next: chain/txn attack.

#define IMG 512
#define NPIX (16LL * 3 * 512 * 512)
#define NG 16                 /* output granules (16 rows) per wave */
#define NBLK (32 * 2 * 48)    /* 3072 one-wave blocks = 12 per CU */
#define NPART NBLK            /* one float per block: 12 KB */

typedef short v8s __attribute__((ext_vector_type(8)));   // 8 x bf16 (4 VGPRs)
typedef float v4f __attribute__((ext_vector_type(4)));   // MFMA accumulator
typedef __bf16 bf2 __attribute__((ext_vector_type(2)));
typedef float f2  __attribute__((ext_vector_type(2)));

static __device__ __forceinline__ int cvtpk2(f2 v) {     // v_cvt_pk_bf16_f32
    bf2 r = __builtin_convertvector(v, bf2);
    return __builtin_bit_cast(int, r);
}
static __device__ __forceinline__ unsigned f2bf(float f) {
    unsigned u = __float_as_uint(f);
    return (u + 0x7FFFu + ((u >> 16) & 1u)) >> 16;
}

// Async 16B/lane global->LDS. Dest is wave-uniform base; lane i lands at
// base + i*16. Source address is per-lane.
static __device__ __forceinline__ void gload16(const float* g, void* lds) {
    __builtin_amdgcn_global_load_lds(
        (const __attribute__((address_space(1))) void*)g,
        (__attribute__((address_space(3))) void*)lds, 16, 0, 0);
}

template <int N>
static __device__ __forceinline__ void vwait() {
    if constexpr (N == 4) asm volatile("s_waitcnt vmcnt(4)" ::: "memory");
    else                  asm volatile("s_waitcnt vmcnt(0)" ::: "memory");
    __builtin_amdgcn_sched_barrier(0);   // keep ds_reads below the wait
}
static __device__ __forceinline__ void lwait0() {
    asm volatile("s_waitcnt lgkmcnt(0)" ::: "memory");
    __builtin_amdgcn_sched_barrier(0);   // rule #18: fence reordering past it
}

// h-pass for one 16-row granule: pack 4 planes to bf16, 4 MFMA, write H ring.
static __device__ __forceinline__ void h_rt(
    const float4 (&L)[4], v8s band, short (*hw)[16][40], int lm, int quad, int slot)
{
    const v4f zacc = {0.f, 0.f, 0.f, 0.f};
    const float4 a0 = L[0], a1 = L[1], b0 = L[2], b1 = L[3];
    f2 a0l; a0l.x = a0.x; a0l.y = a0.y;   f2 a0h; a0h.x = a0.z; a0h.y = a0.w;
    f2 a1l; a1l.x = a1.x; a1l.y = a1.y;   f2 a1h; a1h.x = a1.z; a1h.y = a1.w;
    f2 b0l; b0l.x = b0.x; b0l.y = b0.y;   f2 b0h; b0h.x = b0.z; b0h.y = b0.w;
    f2 b1l; b1l.x = b1.x; b1l.y = b1.y;   f2 b1h; b1h.x = b1.z; b1h.y = b1.w;

    v8s A[4]; int4 w;
    w.x = cvtpk2(a0l); w.y = cvtpk2(a0h); w.z = cvtpk2(a1l); w.w = cvtpk2(a1h);
    A[0] = __builtin_bit_cast(v8s, w);
    w.x = cvtpk2(b0l); w.y = cvtpk2(b0h); w.z = cvtpk2(b1l); w.w = cvtpk2(b1h);
    A[1] = __builtin_bit_cast(v8s, w);
    w.x = cvtpk2(__builtin_elementwise_fma(a0l, a0l, b0l * b0l));
    w.y = cvtpk2(__builtin_elementwise_fma(a0h, a0h, b0h * b0h));
    w.z = cvtpk2(__builtin_elementwise_fma(a1l, a1l, b1l * b1l));
    w.w = cvtpk2(__builtin_elementwise_fma(a1h, a1h, b1h * b1h));
    A[2] = __builtin_bit_cast(v8s, w);
    w.x = cvtpk2(a0l * b0l); w.y = cvtpk2(a0h * b0h);
    w.z = cvtpk2(a1l * b1l); w.w = cvtpk2(a1h * b1h);
    A[3] = __builtin_bit_cast(v8s, w);

    #pragma unroll
    for (int p = 0; p < 4; ++p) {
        const v4f acc = __builtin_amdgcn_mfma_f32_16x16x32_bf16(A[p], band, zacc, 0, 0, 0);
        // D C-layout: col = lm, rows quad*4 + reg -> ring slot, col-major write.
        int2 w2;
        f2 lo; lo.x = acc[0]; lo.y = acc[1];
        f2 hi; hi.x = acc[2]; hi.y = acc[3];
        w2.x = cvtpk2(lo); w2.y = cvtpk2(hi);
        *(int2*)&hw[p][lm][slot * 16 + quad * 4] = w2;
    }
}

// v-pass for output granule o (ring window = granules o, o+1) + SSIM accumulate.
static __device__ __forceinline__ void v_t2(
    v8s band, short (*hw)[16][40], int lm, int quad, int o, f2& vsum)
{
    const v4f zacc = {0.f, 0.f, 0.f, 0.f};
    const int bs = (quad * 8 + o * 16) & 31;   // granule g lives at H slot g&1
    v4f acc[4];
    #pragma unroll
    for (int p = 0; p < 4; ++p) {
        const v8s hf = *(const v8s*)&hw[p][lm][bs];
        acc[p] = __builtin_amdgcn_mfma_f32_16x16x32_bf16(band, hf, zacc, 0, 0, 0);
    }
    const f2 C1v = {1e-4f, 1e-4f};        // 0.01^2
    const f2 C2v = {9e-4f, 9e-4f};        // 0.03^2
    const f2 two = {2.f, 2.f};
    #pragma unroll
    for (int h = 0; h < 2; ++h) {
        f2 m1; m1.x = acc[0][2 * h]; m1.y = acc[0][2 * h + 1];
        f2 m2; m2.x = acc[1][2 * h]; m2.y = acc[1][2 * h + 1];
        f2 es; es.x = acc[2][2 * h]; es.y = acc[2][2 * h + 1];
        f2 ex; ex.x = acc[3][2 * h]; ex.y = acc[3][2 * h + 1];
        const f2 m1s = m1 * m1, m2s = m2 * m2, m12 = m1 * m2;
        const f2 sig = es - m1s - m2s;                  // sig1_sq + sig2_sq
        const f2 s12 = ex - m12;
        const f2 num = __builtin_elementwise_fma(two, m12, C1v) *
                       __builtin_elementwise_fma(two, s12, C2v);
        const f2 den = (m1s + m2s + C1v) * (sig + C2v);
        f2 r; r.x = __builtin_amdgcn_rcpf(den.x); r.y = __builtin_amdgcn_rcpf(den.y);
        vsum = __builtin_elementwise_fma(num, r, vsum);
    }
}

__global__ __launch_bounds__(64, 3) void ssim_kernel(
    const float* __restrict__ img1,
    const float* __restrict__ img2,
    const float* __restrict__ win,
    float* __restrict__ partial)
{
    // Per-block (= per-wave) LDS: H ring 5120B + raw ring 8192B = 13312B.
    __shared__ __align__(16) short  hb[4][16][40];
    __shared__ __align__(16) float4 raw[2][4][64];

    const int lane = threadIdx.x;          // 0..63
    const int lm   = lane & 15;
    const int quad = lane >> 4;

    const int gct = blockIdx.x;            // col-tile 0..31
    const int by  = blockIdx.y;            // row strip 0..1
    const int z   = blockIdx.z;            // 0..47
    const int rowbase = by * (NG * 16);

    // Band fragment via shuffle: value g[k-i-3], i = lane&15, k = quad*8+j.
    float gl = 0.f;
    if (lane < 11) gl = win[55 + lane] * rsqrtf(win[60]);
    v8s band;
    #pragma unroll
    for (int j = 0; j < 8; ++j) {
        const int t  = quad * 8 + j - lm - 3;
        const int tc = ((unsigned)t > 10u) ? 11 : t;   // lane 11 holds 0
        band[j] = (short)f2bf(__shfl(gl, tc));
    }

    const size_t zoff = (size_t)z * IMG * IMG;
    const float* p1 = img1 + zoff;
    const float* p2 = img2 + zoff;

    const bool colOK = (gct > 0) & (gct < 31);
    const int gcol = gct * 16 - 8 + quad * 8;          // -8 .. 512
    const int  colA = gcol < 0 ? 0 : (gcol > IMG - 4 ? IMG - 4 : gcol);
    const int  colB = (gcol + 4) < 0 ? 0 : ((gcol + 4) > IMG - 4 ? IMG - 4 : (gcol + 4));
    const bool cbA  = (unsigned)gcol >= (unsigned)IMG;
    const bool cbB  = (unsigned)(gcol + 4) >= (unsigned)IMG;
    const bool topE = (by == 0), botE = (by == 1);

    // Issue granule k's 4 async loads into raw slot k&1 (rows clamped).
    auto issue_g = [&](int k) {
        const int gr  = rowbase + k * 16 - 8 + lm;
        const int grc = gr < 0 ? 0 : (gr > IMG - 1 ? IMG - 1 : gr);
        const float* r1 = p1 + (size_t)grc * IMG;
        const float* r2 = p2 + (size_t)grc * IMG;
        void* s = &raw[k & 1][0][0];
        gload16(r1 + colA, s);
        gload16(r1 + colB, (char*)s + 1024);
        gload16(r2 + colA, (char*)s + 2048);
        gload16(r2 + colB, (char*)s + 3072);
    };
    // Read granule k from LDS into regs + zero-fix edges. lwait0 pins the
    // data into VGPRs before the caller may re-issue this slot (WAR).
    auto read_g = [&](int k, float4 (&L)[4], bool rowsE) {
        L[0] = raw[k & 1][0][lane];
        L[1] = raw[k & 1][1][lane];
        L[2] = raw[k & 1][2][lane];
        L[3] = raw[k & 1][3][lane];
        lwait0();
        if (!colOK || rowsE) {                     // wave-uniform branch
            const int gr = rowbase + k * 16 - 8 + lm;
            const bool rbad = (unsigned)gr >= (unsigned)IMG;
            float4 zz; zz.x = zz.y = zz.z = zz.w = 0.f;
            if (rbad | cbA) { L[0] = zz; L[2] = zz; }
            if (rbad | cbB) { L[1] = zz; L[3] = zz; }
        }
    };

    f2 vsum = {0.f, 0.f};
    float4 L[4];

    // Pipeline: distance-2 issue->consume, vmcnt(4) steady (granule k lands,
    // k+1 stays in flight), tail 4 then 0.
    issue_g(0); issue_g(1);

    // k = 0 (possible top edge)
    vwait<4>(); read_g(0, L, topE);
    issue_g(2);
    h_rt(L, band, hb, lm, quad, 0);

    #pragma unroll
    for (int k = 1; k <= NG - 2; ++k) {            // k = 1..14, fully unrolled
        vwait<4>(); read_g(k, L, false);
        issue_g(k + 2);
        h_rt(L, band, hb, lm, quad, k & 1);
        v_t2(band, hb, lm, quad, k - 1, vsum);
    }

    // k = NG-1 (no more issues)
    vwait<4>(); read_g(NG - 1, L, false);
    h_rt(L, band, hb, lm, quad, (NG - 1) & 1);
    v_t2(band, hb, lm, quad, NG - 2, vsum);

    // k = NG (possible bottom edge)
    vwait<0>(); read_g(NG, L, botE);
    h_rt(L, band, hb, lm, quad, NG & 1);
    v_t2(band, hb, lm, quad, NG - 1, vsum);

    // ---- wave reduction -> per-block partial (no barriers at all) ----
    float vs = vsum.x + vsum.y;
    #pragma unroll
    for (int off = 32; off > 0; off >>= 1)
        vs += __shfl_down(vs, off, 64);
    if (lane == 0)
        partial[(z * 2 + by) * 32 + gct] = vs;
}

__global__ __launch_bounds__(512) void finalize_kernel(
    const float* __restrict__ partial, float* __restrict__ out)
{
    __shared__ float red[8];
    const float4* p4 = (const float4*)partial;
    float s = 0.f;
    #pragma unroll
    for (int i = threadIdx.x; i < NPART / 4; i += 512) {   // 768 float4s
        const float4 t = p4[i];
        s += (t.x + t.y) + (t.z + t.w);
    }
    #pragma unroll
    for (int off = 32; off > 0; off >>= 1)
        s += __shfl_down(s, off, 64);
    if ((threadIdx.x & 63) == 0) red[threadIdx.x >> 6] = s;
    __syncthreads();
    if (threadIdx.x == 0) {
        float t = 0.f;
        #pragma unroll
        for (int i = 0; i < 8; ++i) t += red[i];
        out[0] = 1.0f - t / (float)NPIX;
    }
}

extern "C" void kernel_launch(void* const* d_in, const int* in_sizes, int n_in,
                              void* d_out, int out_size, void* d_ws, size_t ws_size,
                              hipStream_t stream) {
    const float* img1 = (const float*)d_in[0];
    const float* img2 = (const float*)d_in[1];
    const float* win  = (const float*)d_in[2];
    float* partialb = (float*)d_ws;  // NPART floats = 12 KB; fully rewritten each call

    dim3 grid(32, 2, 48);
    ssim_kernel<<<grid, dim3(64), 0, stream>>>(img1, img2, win, partialb);
    finalize_kernel<<<1, dim3(512), 0, stream>>>(partialb, (float*)d_out);
}

// Round 7
// 129.219 us; speedup vs baseline: 1.5601x; 1.5601x over previous
//
#include <hip/hip_runtime.h>

// SSIM fused, v16: COALESCED staging. v15 post-mortem: full-unroll spill
// (WRITE 81MB) + 1-wave blocks capped ~8/CU -> 113us; reverted to v14 base.
// Six-round invariant: 46-53us at occ 16-73%, any staging, any depth ->
// occupancy/depth are not the lever. Little's law (2.2TB/s => ~3KB/CU
// outstanding vs 8-12KB structural) says waves aren't BW-limited: the VMEM
// instructions themselves are slow. Every version loads lane i's 16B from
// row(lm)*2048B + quad*32B: 64 SCATTERED 16B pieces per instruction, zero
// TA merging. Request model: 214MB/16B/256CU ~ 22us floor -> the ~46us.
// v16 = v14 with ONLY the staging pattern changed:
//   - each gload reads 8 rows x 128B CONTIGUOUS (lane L -> row 8g+(L>>3),
//     piece L&7): merges to 128B transactions (8 reqs/instr, was 64).
//   - linear LDS dest => 128B row stride => 16-way readback conflict; fixed
//     by rule-#21 both-sides swizzle: source col-piece ^= (row&7) (global
//     addr pre-swizzle, LDS linear), readback b128 at
//     (lm*128+piece*16)^((lm&7)<<4). Conflict-free per 8-lane group.
//   - clamp+zero-fix edge logic unchanged (garbage only lands in logical
//     positions already flagged cbA/cbB/rbad).
// Geometry/schedule/math = v14 (harness-verified): 256thr, GY=2, 768 blocks,
// 2-slot raw ring vmcnt(4), H ring 2 slots, unroll 2, launch_bounds(256,3).

#define IMG 512
#define NPIX (16LL * 3 * 512 * 512)
#define GX 8                  /* 32 col-tiles / 4 waves per block */
#define GY 2                  /* 512 rows / 256 rows per wave */
#define NG 16                 /* output granules (16 rows) per wave */
#define NBLK (GX * GY * 48)   /* 768 blocks */
#define NPART NBLK            /* one float per block: 3 KB */

typedef short v8s __attribute__((ext_vector_type(8)));   // 8 x bf16 (4 VGPRs)
typedef float v4f __attribute__((ext_vector_type(4)));   // MFMA accumulator
typedef __bf16 bf2 __attribute__((ext_vector_type(2)));
typedef float f2  __attribute__((ext_vector_type(2)));

static __device__ __forceinline__ int cvtpk2(f2 v) {     // v_cvt_pk_bf16_f32
    bf2 r = __builtin_convertvector(v, bf2);
    return __builtin_bit_cast(int, r);
}
static __device__ __forceinline__ unsigned f2bf(float f) {
    unsigned u = __float_as_uint(f);
    return (u + 0x7FFFu + ((u >> 16) & 1u)) >> 16;
}

// Async 16B/lane global->LDS. Dest is wave-uniform base; lane i lands at
// base + i*16. Source address is per-lane.
static __device__ __forceinline__ void gload16(const void* g, void* lds) {
    __builtin_amdgcn_global_load_lds(
        (const __attribute__((address_space(1))) void*)g,
        (__attribute__((address_space(3))) void*)lds, 16, 0, 0);
}

template <int N>
static __device__ __forceinline__ void vwait() {
    if constexpr (N == 4) asm volatile("s_waitcnt vmcnt(4)" ::: "memory");
    else                  asm volatile("s_waitcnt vmcnt(0)" ::: "memory");
    __builtin_amdgcn_sched_barrier(0);   // keep ds_reads below the wait
}
static __device__ __forceinline__ void lwait0() {
    asm volatile("s_waitcnt lgkmcnt(0)" ::: "memory");
    __builtin_amdgcn_sched_barrier(0);   // rule #18: fence reordering past it
}

// h-pass for one 16-row granule: pack 4 planes to bf16, 4 MFMA, write H ring.
static __device__ __forceinline__ void h_rt(
    const float4 (&L)[4], v8s band, short (*hw)[16][40], int lm, int quad, int slot)
{
    const v4f zacc = {0.f, 0.f, 0.f, 0.f};
    const float4 a0 = L[0], a1 = L[1], b0 = L[2], b1 = L[3];
    f2 a0l; a0l.x = a0.x; a0l.y = a0.y;   f2 a0h; a0h.x = a0.z; a0h.y = a0.w;
    f2 a1l; a1l.x = a1.x; a1l.y = a1.y;   f2 a1h; a1h.x = a1.z; a1h.y = a1.w;
    f2 b0l; b0l.x = b0.x; b0l.y = b0.y;   f2 b0h; b0h.x = b0.z; b0h.y = b0.w;
    f2 b1l; b1l.x = b1.x; b1l.y = b1.y;   f2 b1h; b1h.x = b1.z; b1h.y = b1.w;

    v8s A[4]; int4 w;
    w.x = cvtpk2(a0l); w.y = cvtpk2(a0h); w.z = cvtpk2(a1l); w.w = cvtpk2(a1h);
    A[0] = __builtin_bit_cast(v8s, w);
    w.x = cvtpk2(b0l); w.y = cvtpk2(b0h); w.z = cvtpk2(b1l); w.w = cvtpk2(b1h);
    A[1] = __builtin_bit_cast(v8s, w);
    w.x = cvtpk2(__builtin_elementwise_fma(a0l, a0l, b0l * b0l));
    w.y = cvtpk2(__builtin_elementwise_fma(a0h, a0h, b0h * b0h));
    w.z = cvtpk2(__builtin_elementwise_fma(a1l, a1l, b1l * b1l));
    w.w = cvtpk2(__builtin_elementwise_fma(a1h, a1h, b1h * b1h));
    A[2] = __builtin_bit_cast(v8s, w);
    w.x = cvtpk2(a0l * b0l); w.y = cvtpk2(a0h * b0h);
    w.z = cvtpk2(a1l * b1l); w.w = cvtpk2(a1h * b1h);
    A[3] = __builtin_bit_cast(v8s, w);

    #pragma unroll
    for (int p = 0; p < 4; ++p) {
        const v4f acc = __builtin_amdgcn_mfma_f32_16x16x32_bf16(A[p], band, zacc, 0, 0, 0);
        // D C-layout: col = lm, rows quad*4 + reg -> ring slot, col-major write.
        int2 w2;
        f2 lo; lo.x = acc[0]; lo.y = acc[1];
        f2 hi; hi.x = acc[2]; hi.y = acc[3];
        w2.x = cvtpk2(lo); w2.y = cvtpk2(hi);
        *(int2*)&hw[p][lm][slot * 16 + quad * 4] = w2;
    }
}

// v-pass for output granule o (ring window = granules o, o+1) + SSIM accumulate.
static __device__ __forceinline__ void v_t2(
    v8s band, short (*hw)[16][40], int lm, int quad, int o, f2& vsum)
{
    const v4f zacc = {0.f, 0.f, 0.f, 0.f};
    const int bs = (quad * 8 + o * 16) & 31;   // granule g lives at H slot g&1
    v4f acc[4];
    #pragma unroll
    for (int p = 0; p < 4; ++p) {
        const v8s hf = *(const v8s*)&hw[p][lm][bs];
        acc[p] = __builtin_amdgcn_mfma_f32_16x16x32_bf16(band, hf, zacc, 0, 0, 0);
    }
    const f2 C1v = {1e-4f, 1e-4f};        // 0.01^2
    const f2 C2v = {9e-4f, 9e-4f};        // 0.03^2
    const f2 two = {2.f, 2.f};
    #pragma unroll
    for (int h = 0; h < 2; ++h) {
        f2 m1; m1.x = acc[0][2 * h]; m1.y = acc[0][2 * h + 1];
        f2 m2; m2.x = acc[1][2 * h]; m2.y = acc[1][2 * h + 1];
        f2 es; es.x = acc[2][2 * h]; es.y = acc[2][2 * h + 1];
        f2 ex; ex.x = acc[3][2 * h]; ex.y = acc[3][2 * h + 1];
        const f2 m1s = m1 * m1, m2s = m2 * m2, m12 = m1 * m2;
        const f2 sig = es - m1s - m2s;                  // sig1_sq + sig2_sq
        const f2 s12 = ex - m12;
        const f2 num = __builtin_elementwise_fma(two, m12, C1v) *
                       __builtin_elementwise_fma(two, s12, C2v);
        const f2 den = (m1s + m2s + C1v) * (sig + C2v);
        f2 r; r.x = __builtin_amdgcn_rcpf(den.x); r.y = __builtin_amdgcn_rcpf(den.y);
        vsum = __builtin_elementwise_fma(num, r, vsum);
    }
}

__global__ __launch_bounds__(256, 3) void ssim_kernel(
    const float* __restrict__ img1,
    const float* __restrict__ img2,
    const float* __restrict__ win,
    float* __restrict__ partial)
{
    // H ring: [wave][plane][col][40 shorts] = 20480 B (shorts 0-31 = two
    // 16-row slots; pad 32-39; final reduce borrows shorts 36-37 of [3][15]).
    __shared__ __align__(16) short hb[4][4][16][40];
    // Raw ring: [wave][slot][4096B]. Slot = [img][16 rows][128B], rows at
    // 128B stride, cols XOR-swizzled by (row&7). 32768 B; block total 53248.
    __shared__ __align__(16) char raw[4][2][4096];

    const int tid  = threadIdx.x;
    const int lane = tid & 63;
    const int wave = tid >> 6;
    const int lm   = lane & 15;
    const int quad = lane >> 4;

    const int bx = blockIdx.x, by = blockIdx.y, z = blockIdx.z;
    const int rowbase = by * (NG * 16);

    // Band fragment via shuffle: value g[k-i-3], i = lane&15, k = quad*8+j.
    float gl = 0.f;
    if (lane < 11) gl = win[55 + lane] * rsqrtf(win[60]);
    v8s band;
    #pragma unroll
    for (int j = 0; j < 8; ++j) {
        const int t  = quad * 8 + j - lm - 3;
        const int tc = ((unsigned)t > 10u) ? 11 : t;   // lane 11 holds 0
        band[j] = (short)f2bf(__shfl(gl, tc));
    }

    const size_t zoff = (size_t)z * IMG * IMG;
    const char* p1 = (const char*)(img1 + zoff);
    const char* p2 = (const char*)(img2 + zoff);

    // One 16-col tile per wave, 256-row strip.
    const int gct = bx * 4 + wave;
    const bool colOK = (gct > 0) & (gct < 31);
    const int gcol = gct * 16 - 8 + quad * 8;          // reader's float col
    const bool cbA  = (unsigned)gcol >= (unsigned)IMG;
    const bool cbB  = (unsigned)(gcol + 4) >= (unsigned)IMG;
    const bool topE = (by == 0), botE = (by == GY - 1);
    short (*hw)[16][40] = hb[wave];

    // ---- coalesced staging maps (per-lane constants) ----
    // Loader lane L of gload g: source row = 8g + (L>>3), logical col-piece
    // = (L&7) ^ ((L>>3)&7)  (source-side swizzle; LDS dest stays linear).
    const int rowoff = lane >> 3;                       // 0..7
    int cb = gct * 64 - 32 + (((lane & 7) ^ (rowoff & 7)) << 4);
    cb = cb < 0 ? 0 : (cb > 2032 ? 2032 : cb);          // clamp into row
    const int colbyte = cb;
    // Reader lane (lm,quad): pieces 2q,2q+1 of row lm, swizzled readback.
    const int off0 = lm * 128 + (((2 * quad)     ^ (lm & 7)) << 4);
    const int off1 = lm * 128 + (((2 * quad + 1) ^ (lm & 7)) << 4);

    // Issue granule k's 4 async loads into raw slot k&1. Each instruction
    // reads 8 rows x 128B CONTIGUOUS (full TA merging).
    auto issue_g = [&](int k) {
        const int rb = rowbase + k * 16 - 8;
        int r0 = rb + rowoff;      r0 = r0 < 0 ? 0 : (r0 > IMG - 1 ? IMG - 1 : r0);
        int r1 = rb + 8 + rowoff;  r1 = r1 < 0 ? 0 : (r1 > IMG - 1 ? IMG - 1 : r1);
        char* s = &raw[wave][k & 1][0];
        gload16(p1 + (size_t)r0 * 2048 + colbyte, s);
        gload16(p1 + (size_t)r1 * 2048 + colbyte, s + 1024);
        gload16(p2 + (size_t)r0 * 2048 + colbyte, s + 2048);
        gload16(p2 + (size_t)r1 * 2048 + colbyte, s + 3072);
    };
    // Read granule k from LDS into regs + zero-fix edges. lwait0 pins the
    // data into VGPRs before the caller may re-issue this slot (WAR).
    auto read_g = [&](int k, float4 (&L)[4], bool rowsE) {
        const char* s = &raw[wave][k & 1][0];
        L[0] = *(const float4*)(s + off0);
        L[1] = *(const float4*)(s + off1);
        L[2] = *(const float4*)(s + off0 + 2048);
        L[3] = *(const float4*)(s + off1 + 2048);
        lwait0();
        if (!colOK || rowsE) {                     // wave-uniform branch
            const int gr = rowbase + k * 16 - 8 + lm;
            const bool rbad = (unsigned)gr >= (unsigned)IMG;
            float4 zz; zz.x = zz.y = zz.z = zz.w = 0.f;
            if (rbad | cbA) { L[0] = zz; L[2] = zz; }
            if (rbad | cbB) { L[1] = zz; L[3] = zz; }
        }
    };

    f2 vsum = {0.f, 0.f};
    float4 L[4];

    // Pipeline: distance-2 issue->consume, vmcnt(4) steady (granule k lands,
    // k+1 stays in flight), tail 4 then 0.
    issue_g(0); issue_g(1);

    // k = 0 (possible top edge)
    vwait<4>(); read_g(0, L, topE);
    issue_g(2);
    h_rt(L, band, hw, lm, quad, 0);

    #pragma unroll 2
    for (int k = 1; k <= NG - 2; ++k) {            // k = 1..14
        vwait<4>(); read_g(k, L, false);
        issue_g(k + 2);
        h_rt(L, band, hw, lm, quad, k & 1);
        v_t2(band, hw, lm, quad, k - 1, vsum);
    }

    // k = NG-1 (no more issues)
    vwait<4>(); read_g(NG - 1, L, false);
    h_rt(L, band, hw, lm, quad, (NG - 1) & 1);
    v_t2(band, hw, lm, quad, NG - 2, vsum);

    // k = NG (possible bottom edge)
    vwait<0>(); read_g(NG, L, botE);
    h_rt(L, band, hw, lm, quad, NG & 1);
    v_t2(band, hw, lm, quad, NG - 1, vsum);

    // ---- wave reduction, then per-BLOCK partial via LDS pad slots ----
    float vs = vsum.x + vsum.y;
    #pragma unroll
    for (int off = 32; off > 0; off >>= 1)
        vs += __shfl_down(vs, off, 64);
    if (lane == 0) *(float*)&hb[wave][3][15][36] = vs;   // pad, wave-private
    __syncthreads();
    if (tid == 0) {
        float t = 0.f;
        #pragma unroll
        for (int w = 0; w < 4; ++w) t += *(const float*)&hb[w][3][15][36];
        partial[(z * GY + by) * GX + bx] = t;
    }
}

__global__ __launch_bounds__(512) void finalize_kernel(
    const float* __restrict__ partial, float* __restrict__ out)
{
    __shared__ float red[8];
    float s = 0.f;
    if (threadIdx.x < NPART / 4) {                      // 192 float4s
        const float4 t = ((const float4*)partial)[threadIdx.x];
        s = (t.x + t.y) + (t.z + t.w);
    }
    #pragma unroll
    for (int off = 32; off > 0; off >>= 1)
        s += __shfl_down(s, off, 64);
    if ((threadIdx.x & 63) == 0) red[threadIdx.x >> 6] = s;
    __syncthreads();
    if (threadIdx.x == 0) {
        float t = 0.f;
        #pragma unroll
        for (int i = 0; i < 8; ++i) t += red[i];
        out[0] = 1.0f - t / (float)NPIX;
    }
}

extern "C" void kernel_launch(void* const* d_in, const int* in_sizes, int n_in,
                              void* d_out, int out_size, void* d_ws, size_t ws_size,
                              hipStream_t stream) {
    const float* img1 = (const float*)d_in[0];
    const float* img2 = (const float*)d_in[1];
    const float* win  = (const float*)d_in[2];
    float* partialb = (float*)d_ws;  // NPART floats = 3 KB; fully rewritten each call

    dim3 grid(GX, GY, 48);
    ssim_kernel<<<grid, dim3(256), 0, stream>>>(img1, img2, win, partialb);
    finalize_kernel<<<1, dim3(512), 0, stream>>>(partialb, (float*)d_out);
}